// Round 7
// baseline (151.807 us; speedup 1.0000x reference)
//
#include <hip/hip_runtime.h>
#include <hip/hip_bf16.h>

#define N_PTS 8192
#define M_PTS 8192
#define DIM   512
#define NB    (N_PTS/256)   // 32 n-blocks (256-row tiles)

typedef __attribute__((ext_vector_type(8))) short bf8_t;    // 8 bf16
typedef __attribute__((ext_vector_type(8))) unsigned short us8_t;
typedef __attribute__((ext_vector_type(4))) float f4_t;

// workspace layout (bytes)
constexpr size_t ZB_OFF   = 0;                                        // bf16 panels of z: 8 MiB
constexpr size_t EB_OFF   = (size_t)N_PTS * DIM * 2;                  // bf16 panels of e: 8 MiB
constexpr size_t Z2_OFF   = EB_OFF + (size_t)M_PTS * DIM * 2;         // f32 row norms z
constexpr size_t E2_OFF   = Z2_OFF + (size_t)N_PTS * 4;
constexpr size_t PMAX_OFF = E2_OFF + (size_t)M_PTS * 4;               // f32 [NB][M]
constexpr size_t PSUM_OFF = PMAX_OFF + (size_t)NB * M_PTS * 4;        // f32 [NB][M]
constexpr size_t SUM_OFF  = PSUM_OFF + (size_t)NB * M_PTS * 4;        // double accumulator
constexpr size_t CNT_OFF  = SUM_OFF + 8;                              // int counter

__device__ __forceinline__ unsigned short f2bf(float x) {
  __hip_bfloat16 h = __float2bfloat16(x);
  return __builtin_bit_cast(unsigned short, h);
}

__device__ __forceinline__ void gload_lds16(const void* g, void* l) {
  __builtin_amdgcn_global_load_lds(
      (const __attribute__((address_space(1))) unsigned int*)g,
      (__attribute__((address_space(3))) unsigned int*)l, 16, 0, 0);
}

#define BAR()         __builtin_amdgcn_s_barrier()
#define SFENCE()      __builtin_amdgcn_sched_barrier(0)
#define WAIT_VM0()    asm volatile("s_waitcnt vmcnt(0)" ::: "memory")

// ---------------------------------------------------------------------------
// Kernel 1: f32 -> bf16 panel-major swizzled layout + f32 row squared norms.
// Panel pi = (row>>7)*8 + (k>>6): 128 rows x 64 k bf16 = 16 KiB contiguous.
// Within panel: byte = (r*128 + c*2) ^ ((r&7)<<4)  (XOR pre-baked in the
// GLOBAL image; gload_lds writes LDS linearly, ds_read re-applies the XOR).
// One wave per row. Also zero-inits the loss accumulator (re-poison-safe).
// ---------------------------------------------------------------------------
__global__ __launch_bounds__(256) void conv_kernel(const float* __restrict__ z,
                                                   const float* __restrict__ e,
                                                   char* __restrict__ ws) {
  const int tid = threadIdx.x;
  const int g = blockIdx.x * 4 + (tid >> 6);     // 0..16383
  const bool isE = g >= N_PTS;
  const int row = isE ? (g - N_PTS) : g;
  const float* src = (isE ? e : z) + (size_t)row * DIM;
  char* panels = ws + (isE ? EB_OFF : ZB_OFF);
  float* rowsq = (float*)(ws + (isE ? E2_OFF : Z2_OFF));

  if (g == 0 && tid == 0) {                      // init for combine_finalize
    *(double*)(ws + SUM_OFF) = 0.0;
    *(int*)(ws + CNT_OFF) = 0;
  }

  const int idx = tid & 63;                      // lane: 8 f32 each
  float4 v0 = ((const float4*)src)[idx * 2];
  float4 v1 = ((const float4*)src)[idx * 2 + 1];
  float ss = v0.x*v0.x + v0.y*v0.y + v0.z*v0.z + v0.w*v0.w
           + v1.x*v1.x + v1.y*v1.y + v1.z*v1.z + v1.w*v1.w;

  us8_t bv;
  bv[0] = f2bf(v0.x); bv[1] = f2bf(v0.y); bv[2] = f2bf(v0.z); bv[3] = f2bf(v0.w);
  bv[4] = f2bf(v1.x); bv[5] = f2bf(v1.y); bv[6] = f2bf(v1.z); bv[7] = f2bf(v1.w);

  const int pi = (row >> 7) * 8 + (idx >> 3);
  const int r = row & 127;
  const int c16 = (idx & 7) * 16;                // byte col within panel
  const int byteoff = (r * 128 + c16) ^ ((r & 7) << 4);   // 16B-aligned
  *(us8_t*)(panels + (size_t)pi * 16384 + byteoff) = bv;

  #pragma unroll
  for (int mk = 32; mk >= 1; mk >>= 1) ss += __shfl_xor(ss, mk, 64);
  if (idx == 0) rowsq[row] = ss;
}

// ---------------------------------------------------------------------------
// Kernel 2: 256x256 tile GEMM (z . e^T), BK=64, 8 waves (2Mx4N), per-wave
// 128x64 output. ONE inter-wave rendezvous per K-tile (vmcnt(0)+s_barrier at
// the tile boundary); quadrant phases separated only by sched_barrier(0)
// fences (zero-cost, per-wave) — they pin the read/MFMA structure for the
// register allocator (round-3 spill lesson) without CU-wide sync. Round-6
// had 9 s_barrier + 3 lgkmcnt(0) per tile = the 33% all-stall gap.
// Staging spread 2 gloads per quadrant so the newest load is >=1 quadrant
// (~300cyc >= L2 latency) old at the boundary drain. L2-chunked block
// mapping (8 nblk x 4 mblk per XCD). Fused online max/sumexp epilogue.
// ---------------------------------------------------------------------------
__global__ __launch_bounds__(512, 2) void gemm_lse_kernel(char* __restrict__ ws,
                                                          const float* __restrict__ log_sigma) {
  __shared__ char lds[131072] __attribute__((aligned(16)));

  const int tid  = threadIdx.x;
  const int lane = tid & 63;
  const int wv   = tid >> 6;     // 0..7
  const int wr   = wv >> 2;      // 0..1  (z row-half of tile)
  const int wc   = wv & 3;       // 0..3  (e col quarter)

  // Chunked mapping: bid&7 ~ XCD; the 32 blocks concurrently resident per
  // XCD (stride-8 bids) tile an 8(nblk) x 4(mblk) rect -> 3 MB < 4 MB L2.
  const int bid  = blockIdx.x;          // 0..1023
  const int x    = bid & 7;
  const int q    = bid >> 3;            // 0..127
  const int w    = q >> 5;              // sequential round 0..3
  const int s    = q & 31;              // slot in concurrent set
  const int rect = w * 8 + x;           // 0..31
  const int nblk = (rect & 3) * 8 + (s & 7);
  const int mblk = (rect >> 2) * 4 + (s >> 3);

  const char* zb = ws + ZB_OFF;
  const char* eb = ws + EB_OFF;
  const char* pb0 = zb + (size_t)(nblk * 16) * 16384;
  const char* pb1 = zb + (size_t)(nblk * 16 + 8) * 16384;
  const char* pb2 = eb + (size_t)(mblk * 16) * 16384;
  const char* pb3 = eb + (size_t)(mblk * 16 + 8) * 16384;
  const char* mypanel = (wv >> 1) == 0 ? pb0 : (wv >> 1) == 1 ? pb1 : (wv >> 1) == 2 ? pb2 : pb3;
  const int stage_goff = (wv & 1) * 8192 + lane * 16;          // per-lane global
  const int stage_loff = (wv >> 1) * 16384 + (wv & 1) * 8192;  // wave-uniform LDS

// 2 of this wave's 8 tile-loads (quarter qt of its 8KB share)
#define STAGE2(cur, kb, qt) do { \
    _Pragma("unroll") \
    for (int i_ = 0; i_ < 2; ++i_) \
      gload_lds16(mypanel + (size_t)(kb) * 16384 + stage_goff + ((qt) * 2 + i_) * 1024, \
                  lds + (cur) * 65536 + stage_loff + ((qt) * 2 + i_) * 1024); \
  } while (0)

  const int rl  = lane & 15;
  const int kq  = (lane >> 4) * 16;
  const int swz = (rl & 7) << 4;
  // the ONLY per-lane address terms (ks=0 / ks=1); all else uniform/imm
  const int adyn0 = rl * 128 + (kq ^ swz);
  const int adyn1 = rl * 128 + ((64 + kq) ^ swz);

  bf8_t fA[4][2];      // current A-half: 4 frags x 2 k-steps  (32 VGPR)
  bf8_t fB[2][2][2];   // [jhalf][jfrag][kstep]                (32 VGPR)
  f4_t acc[8][4] = {}; // 128 regs

#define READ_A(ih, cur) do { \
    _Pragma("unroll") \
    for (int f_ = 0; f_ < 4; ++f_) { \
      fA[f_][0] = *(const bf8_t*)(lds + (cur) * 65536 + wr * 16384 + (ih) * 8192 + f_ * 2048 + adyn0); \
      fA[f_][1] = *(const bf8_t*)(lds + (cur) * 65536 + wr * 16384 + (ih) * 8192 + f_ * 2048 + adyn1); \
    } \
  } while (0)

#define READ_B(jh, cur) do { \
    _Pragma("unroll") \
    for (int jf_ = 0; jf_ < 2; ++jf_) { \
      const int ub_ = (cur) * 65536 + 32768 + (wc >> 1) * 16384 + (wc & 1) * 8192 + ((jh) * 2 + jf_) * 2048; \
      fB[jh][jf_][0] = *(const bf8_t*)(lds + ub_ + adyn0); \
      fB[jh][jf_][1] = *(const bf8_t*)(lds + ub_ + adyn1); \
    } \
  } while (0)

#define MFMA_Q(ih, jh) do { \
    __builtin_amdgcn_s_setprio(1); \
    _Pragma("unroll") \
    for (int i_ = 0; i_ < 4; ++i_) \
      _Pragma("unroll") \
      for (int jf_ = 0; jf_ < 2; ++jf_) \
        _Pragma("unroll") \
        for (int ks_ = 0; ks_ < 2; ++ks_) \
          acc[(ih) * 4 + i_][(jh) * 2 + jf_] = __builtin_amdgcn_mfma_f32_16x16x32_bf16( \
              fA[i_][ks_], fB[jh][jf_][ks_], acc[(ih) * 4 + i_][(jh) * 2 + jf_], 0, 0, 0); \
    __builtin_amdgcn_s_setprio(0); \
  } while (0)

  // prologue: stage tile 0 into buf0, drain, barrier
  STAGE2(0, 0, 0); STAGE2(0, 0, 1); STAGE2(0, 0, 2); STAGE2(0, 0, 3);
  WAIT_VM0(); SFENCE(); BAR(); SFENCE();

  for (int kb = 0; kb < 8; ++kb) {
    const int cur = kb & 1;
    // Q00: stage quarter 0 of next tile; read A0+B0 (compiler inserts fine
    // lgkmcnt before first dependent MFMA — no inter-wave sync needed)
    if (kb + 1 < 8) STAGE2(cur ^ 1, kb + 1, 0);
    READ_A(0, cur);
    READ_B(0, cur);
    MFMA_Q(0, 0);
    SFENCE();
    // Q01: stage quarter 1; read B1
    if (kb + 1 < 8) STAGE2(cur ^ 1, kb + 1, 1);
    READ_B(1, cur);
    MFMA_Q(0, 1);
    SFENCE();
    // Q10: stage quarter 2; read A1 (overwrites fA)
    if (kb + 1 < 8) STAGE2(cur ^ 1, kb + 1, 2);
    READ_A(1, cur);
    MFMA_Q(1, 0);
    SFENCE();
    // Q11: stage quarter 3
    if (kb + 1 < 8) STAGE2(cur ^ 1, kb + 1, 3);
    MFMA_Q(1, 1);
    SFENCE();
    // boundary (the ONLY rendezvous): own staged loads drained, then barrier
    // so every wave's loads for tile kb+1 are visible & every wave is done
    // reading buf cur before it gets restaged next iteration.
    WAIT_VM0(); SFENCE(); BAR(); SFENCE();
  }

#undef STAGE2
#undef READ_A
#undef READ_B
#undef MFMA_Q

  // ---- epilogue: v = sc*(|z|^2+|e|^2) + (-2 sc)*dot ; per-column online max/sumexp
  const float lsv = log_sigma[0];
  const float sc  = -0.5f * __expf(-2.0f * lsv);
  const float n2s = -2.0f * sc;

  float z2v[8][4];
  {
    const float* z2p = (const float*)(ws + Z2_OFF) + nblk * 256 + wr * 128 + ((lane >> 4) << 2);
    #pragma unroll
    for (int i = 0; i < 8; ++i)
      #pragma unroll
      for (int r = 0; r < 4; ++r) z2v[i][r] = z2p[i * 16 + r];
  }
  float e2v[4];
  {
    const float* e2p = (const float*)(ws + E2_OFF) + mblk * 256 + wc * 64 + rl;
    #pragma unroll
    for (int j = 0; j < 4; ++j) e2v[j] = e2p[j * 16];
  }

  float* lmax = (float*)lds;              // [2][256] reuse (all LDS reads drained)
  float* lsum = (float*)(lds + 2048);

  #pragma unroll
  for (int j = 0; j < 4; ++j) {
    float mx = -1e30f;
    #pragma unroll
    for (int i = 0; i < 8; ++i)
      #pragma unroll
      for (int r = 0; r < 4; ++r) {
        float v = fmaf(n2s, acc[i][j][r], sc * (z2v[i][r] + e2v[j]));
        acc[i][j][r] = v;                 // in-place: no vals[] register cost
        mx = fmaxf(mx, v);
      }
    float sm = 0.0f;
    #pragma unroll
    for (int i = 0; i < 8; ++i)
      #pragma unroll
      for (int r = 0; r < 4; ++r) sm += __expf(acc[i][j][r] - mx);

    // fold the 4 lanes sharing a column (lane ^16, ^32)
    #pragma unroll
    for (int mk = 16; mk <= 32; mk <<= 1) {
      float om = __shfl_xor(mx, mk, 64);
      float os = __shfl_xor(sm, mk, 64);
      float nm = fmaxf(mx, om);
      sm = sm * __expf(mx - nm) + os * __expf(om - nm);
      mx = nm;
    }
    if (lane < 16) {
      const int col = wc * 64 + j * 16 + lane;
      lmax[wr * 256 + col] = mx;
      lsum[wr * 256 + col] = sm;
    }
  }
  __syncthreads();

  if (tid < 256) {
    const float m0 = lmax[tid],       s0 = lsum[tid];
    const float m1 = lmax[256 + tid], s1 = lsum[256 + tid];
    const float Mx = fmaxf(m0, m1);
    const float S  = s0 * __expf(m0 - Mx) + s1 * __expf(m1 - Mx);
    float* pmax = (float*)(ws + PMAX_OFF);
    float* psum = (float*)(ws + PSUM_OFF);
    const size_t idx = (size_t)nblk * M_PTS + mblk * 256 + tid;
    pmax[idx] = Mx;
    psum[idx] = S;
  }
}

// ---------------------------------------------------------------------------
// Kernel 3: combine 32 n-block partials per column -> lse[m]; block-reduce
// the lse sum; atomicAdd into ws; last-done block writes the final loss.
// ---------------------------------------------------------------------------
__global__ __launch_bounds__(256) void combine_finalize_kernel(char* __restrict__ ws,
                                                               const float* __restrict__ log_sigma,
                                                               float* __restrict__ out) {
  const int m = blockIdx.x * 256 + threadIdx.x;   // 8192 total
  const float* pmax = (const float*)(ws + PMAX_OFF);
  const float* psum = (const float*)(ws + PSUM_OFF);
  float Mx = pmax[m];
  float S  = psum[m];
  #pragma unroll
  for (int nb = 1; nb < NB; ++nb) {
    const float pm = pmax[(size_t)nb * M_PTS + m];
    const float ps = psum[(size_t)nb * M_PTS + m];
    const float nm = fmaxf(Mx, pm);
    S = S * __expf(Mx - nm) + ps * __expf(pm - nm);
    Mx = nm;
  }
  double lse = (double)Mx + (double)logf(S);

  #pragma unroll
  for (int mk = 32; mk >= 1; mk >>= 1) lse += __shfl_xor(lse, mk, 64);
  __shared__ double red[4];
  if ((threadIdx.x & 63) == 0) red[threadIdx.x >> 6] = lse;
  __syncthreads();
  if (threadIdx.x == 0) {
    const double part = red[0] + red[1] + red[2] + red[3];
    double* sum = (double*)(ws + SUM_OFF);
    int* cnt = (int*)(ws + CNT_OFF);
    atomicAdd(sum, part);
    __threadfence();
    const int old = atomicAdd(cnt, 1);
    if (old == (M_PTS / 256) - 1) {
      const double total = atomicAdd(sum, 0.0);   // coherent read
      const double ls = (double)log_sigma[0];
      const double loss = -total / (double)M_PTS
                          + 0.5 * (double)DIM * (2.0 * ls - 1.0)
                          + log((double)N_PTS);
      out[0] = (float)loss;
    }
  }
}

extern "C" void kernel_launch(void* const* d_in, const int* in_sizes, int n_in,
                              void* d_out, int out_size, void* d_ws, size_t ws_size,
                              hipStream_t stream) {
  const float* z  = (const float*)d_in[0];
  const float* e  = (const float*)d_in[1];
  const float* ls = (const float*)d_in[2];
  float* out = (float*)d_out;
  char* ws = (char*)d_ws;

  conv_kernel<<<(N_PTS + M_PTS) / 4, 256, 0, stream>>>(z, e, ws);
  gemm_lse_kernel<<<(M_PTS / 256) * (N_PTS / 256), 512, 0, stream>>>(ws, ls);
  combine_finalize_kernel<<<M_PTS / 256, 256, 0, stream>>>(ws, ls, out);
}

// Round 9
// 145.163 us; speedup vs baseline: 1.0458x; 1.0458x over previous
//
#include <hip/hip_runtime.h>
#include <hip/hip_bf16.h>

#define N_PTS 8192
#define M_PTS 8192
#define DIM   512
#define NB    (N_PTS/256)   // 32 n-blocks (256-row tiles)

typedef __attribute__((ext_vector_type(8))) short bf8_t;    // 8 bf16
typedef __attribute__((ext_vector_type(8))) unsigned short us8_t;
typedef __attribute__((ext_vector_type(4))) float f4_t;

// workspace layout (bytes)
constexpr size_t ZB_OFF   = 0;                                        // bf16 panels of z: 8 MiB
constexpr size_t EB_OFF   = (size_t)N_PTS * DIM * 2;                  // bf16 panels of e: 8 MiB
constexpr size_t Z2_OFF   = EB_OFF + (size_t)M_PTS * DIM * 2;         // f32 row norms z
constexpr size_t E2_OFF   = Z2_OFF + (size_t)N_PTS * 4;
constexpr size_t PMAX_OFF = E2_OFF + (size_t)M_PTS * 4;               // f32 [NB][M]
constexpr size_t PSUM_OFF = PMAX_OFF + (size_t)NB * M_PTS * 4;        // f32 [NB][M]
constexpr size_t SUM_OFF  = PSUM_OFF + (size_t)NB * M_PTS * 4;        // double accumulator
constexpr size_t CNT_OFF  = SUM_OFF + 8;                              // int counter

__device__ __forceinline__ unsigned short f2bf(float x) {
  __hip_bfloat16 h = __float2bfloat16(x);
  return __builtin_bit_cast(unsigned short, h);
}

__device__ __forceinline__ void gload_lds16(const void* g, void* l) {
  __builtin_amdgcn_global_load_lds(
      (const __attribute__((address_space(1))) unsigned int*)g,
      (__attribute__((address_space(3))) unsigned int*)l, 16, 0, 0);
}

#define BAR()         __builtin_amdgcn_s_barrier()
#define SFENCE()      __builtin_amdgcn_sched_barrier(0)
#define WAIT_VM0()    asm volatile("s_waitcnt vmcnt(0)" ::: "memory")

// ---------------------------------------------------------------------------
// Kernel 1: f32 -> bf16 panel-major swizzled layout + f32 row squared norms.
// Panel pi = (row>>7)*8 + (k>>6): 128 rows x 64 k bf16 = 16 KiB contiguous.
// Within panel: byte = (r*128 + c*2) ^ ((r&7)<<4)  (XOR pre-baked in the
// GLOBAL image; gload_lds writes LDS linearly, ds_read re-applies the XOR).
// One wave per row. Also zero-inits the loss accumulator (re-poison-safe).
// ---------------------------------------------------------------------------
__global__ __launch_bounds__(256) void conv_kernel(const float* __restrict__ z,
                                                   const float* __restrict__ e,
                                                   char* __restrict__ ws) {
  const int tid = threadIdx.x;
  const int g = blockIdx.x * 4 + (tid >> 6);     // 0..16383
  const bool isE = g >= N_PTS;
  const int row = isE ? (g - N_PTS) : g;
  const float* src = (isE ? e : z) + (size_t)row * DIM;
  char* panels = ws + (isE ? EB_OFF : ZB_OFF);
  float* rowsq = (float*)(ws + (isE ? E2_OFF : Z2_OFF));

  if (g == 0 && tid == 0) {                      // init for combine_finalize
    *(double*)(ws + SUM_OFF) = 0.0;
    *(int*)(ws + CNT_OFF) = 0;
  }

  const int idx = tid & 63;                      // lane: 8 f32 each
  float4 v0 = ((const float4*)src)[idx * 2];
  float4 v1 = ((const float4*)src)[idx * 2 + 1];
  float ss = v0.x*v0.x + v0.y*v0.y + v0.z*v0.z + v0.w*v0.w
           + v1.x*v1.x + v1.y*v1.y + v1.z*v1.z + v1.w*v1.w;

  us8_t bv;
  bv[0] = f2bf(v0.x); bv[1] = f2bf(v0.y); bv[2] = f2bf(v0.z); bv[3] = f2bf(v0.w);
  bv[4] = f2bf(v1.x); bv[5] = f2bf(v1.y); bv[6] = f2bf(v1.z); bv[7] = f2bf(v1.w);

  const int pi = (row >> 7) * 8 + (idx >> 3);
  const int r = row & 127;
  const int c16 = (idx & 7) * 16;                // byte col within panel
  const int byteoff = (r * 128 + c16) ^ ((r & 7) << 4);   // 16B-aligned
  *(us8_t*)(panels + (size_t)pi * 16384 + byteoff) = bv;

  #pragma unroll
  for (int mk = 32; mk >= 1; mk >>= 1) ss += __shfl_xor(ss, mk, 64);
  if (idx == 0) rowsq[row] = ss;
}

// ---------------------------------------------------------------------------
// Kernel 2: 256x256 tile GEMM (z . e^T), BK=64, 8 waves (2Mx4N), per-wave
// 128x64 output. One rendezvous per K-tile. ROUND-8 CHANGES:
//  (a) MFMA clusters ordered ks-OUTERMOST: dependency distance between the
//      two accumulating MFMAs on each acc reg grows 1 -> 8 instructions
//      (round-7 had back-to-back dependent pairs = the ~50% issue stall);
//  (b) all 8 prefetch loads issue in Q00/Q01 (round-7 issued the last 2 in
//      Q11, leaving the boundary vmcnt(0) only ~1 quadrant of cover).
// ---------------------------------------------------------------------------
__global__ __launch_bounds__(512, 2) void gemm_lse_kernel(char* __restrict__ ws,
                                                          const float* __restrict__ log_sigma) {
  __shared__ char lds[131072] __attribute__((aligned(16)));

  const int tid  = threadIdx.x;
  const int lane = tid & 63;
  const int wv   = tid >> 6;     // 0..7
  const int wr   = wv >> 2;      // 0..1  (z row-half of tile)
  const int wc   = wv & 3;       // 0..3  (e col quarter)

  // Chunked mapping: bid&7 ~ XCD; the 32 blocks concurrently resident per
  // XCD (stride-8 bids) tile an 8(nblk) x 4(mblk) rect -> 3 MB < 4 MB L2.
  const int bid  = blockIdx.x;          // 0..1023
  const int x    = bid & 7;
  const int q    = bid >> 3;            // 0..127
  const int w    = q >> 5;              // sequential round 0..3
  const int s    = q & 31;              // slot in concurrent set
  const int rect = w * 8 + x;           // 0..31
  const int nblk = (rect & 3) * 8 + (s & 7);
  const int mblk = (rect >> 2) * 4 + (s >> 3);

  const char* zb = ws + ZB_OFF;
  const char* eb = ws + EB_OFF;
  const char* pb0 = zb + (size_t)(nblk * 16) * 16384;
  const char* pb1 = zb + (size_t)(nblk * 16 + 8) * 16384;
  const char* pb2 = eb + (size_t)(mblk * 16) * 16384;
  const char* pb3 = eb + (size_t)(mblk * 16 + 8) * 16384;
  const char* mypanel = (wv >> 1) == 0 ? pb0 : (wv >> 1) == 1 ? pb1 : (wv >> 1) == 2 ? pb2 : pb3;
  const int stage_goff = (wv & 1) * 8192 + lane * 16;          // per-lane global
  const int stage_loff = (wv >> 1) * 16384 + (wv & 1) * 8192;  // wave-uniform LDS

// 4 of this wave's 8 tile-loads (half h of its 8KB share)
#define STAGE4(cur, kb, h) do { \
    _Pragma("unroll") \
    for (int i_ = 0; i_ < 4; ++i_) \
      gload_lds16(mypanel + (size_t)(kb) * 16384 + stage_goff + ((h) * 4 + i_) * 1024, \
                  lds + (cur) * 65536 + stage_loff + ((h) * 4 + i_) * 1024); \
  } while (0)

  const int rl  = lane & 15;
  const int kq  = (lane >> 4) * 16;
  const int swz = (rl & 7) << 4;
  // the ONLY per-lane address terms (ks=0 / ks=1); all else uniform/imm
  const int adyn0 = rl * 128 + (kq ^ swz);
  const int adyn1 = rl * 128 + ((64 + kq) ^ swz);

  bf8_t fA[4][2];      // current A-half: 4 frags x 2 k-steps  (32 VGPR)
  bf8_t fB[2][2][2];   // [jhalf][jfrag][kstep]                (32 VGPR)
  f4_t acc[8][4] = {}; // 128 regs

#define READ_A(ih, cur) do { \
    _Pragma("unroll") \
    for (int f_ = 0; f_ < 4; ++f_) { \
      fA[f_][0] = *(const bf8_t*)(lds + (cur) * 65536 + wr * 16384 + (ih) * 8192 + f_ * 2048 + adyn0); \
      fA[f_][1] = *(const bf8_t*)(lds + (cur) * 65536 + wr * 16384 + (ih) * 8192 + f_ * 2048 + adyn1); \
    } \
  } while (0)

#define READ_B(jh, cur) do { \
    _Pragma("unroll") \
    for (int jf_ = 0; jf_ < 2; ++jf_) { \
      const int ub_ = (cur) * 65536 + 32768 + (wc >> 1) * 16384 + (wc & 1) * 8192 + ((jh) * 2 + jf_) * 2048; \
      fB[jh][jf_][0] = *(const bf8_t*)(lds + ub_ + adyn0); \
      fB[jh][jf_][1] = *(const bf8_t*)(lds + ub_ + adyn1); \
    } \
  } while (0)

// ks OUTERMOST: 8 independent accs issue between the dependent ks=0/ks=1
// accumulations on any given acc register (dep distance 8 instrs).
#define MFMA_Q(ih, jh) do { \
    __builtin_amdgcn_s_setprio(1); \
    _Pragma("unroll") \
    for (int ks_ = 0; ks_ < 2; ++ks_) \
      _Pragma("unroll") \
      for (int i_ = 0; i_ < 4; ++i_) \
        _Pragma("unroll") \
        for (int jf_ = 0; jf_ < 2; ++jf_) \
          acc[(ih) * 4 + i_][(jh) * 2 + jf_] = __builtin_amdgcn_mfma_f32_16x16x32_bf16( \
              fA[i_][ks_], fB[jh][jf_][ks_], acc[(ih) * 4 + i_][(jh) * 2 + jf_], 0, 0, 0); \
    __builtin_amdgcn_s_setprio(0); \
  } while (0)

  // prologue: stage tile 0 into buf0, drain, barrier
  STAGE4(0, 0, 0); STAGE4(0, 0, 1);
  WAIT_VM0(); SFENCE(); BAR(); SFENCE();

  for (int kb = 0; kb < 8; ++kb) {
    const int cur = kb & 1;
    // Q00: stage first half of next tile; read A0+B0
    if (kb + 1 < 8) STAGE4(cur ^ 1, kb + 1, 0);
    READ_A(0, cur);
    READ_B(0, cur);
    MFMA_Q(0, 0);
    SFENCE();
    // Q01: stage second half; read B1
    if (kb + 1 < 8) STAGE4(cur ^ 1, kb + 1, 1);
    READ_B(1, cur);
    MFMA_Q(0, 1);
    SFENCE();
    // Q10: read A1 (overwrites fA)
    READ_A(1, cur);
    MFMA_Q(1, 0);
    SFENCE();
    // Q11
    MFMA_Q(1, 1);
    SFENCE();
    // boundary (the ONLY rendezvous): own staged loads (issued >=2 quadrants
    // ago) drained, then barrier -> tile kb+1 visible, buf cur free.
    WAIT_VM0(); SFENCE(); BAR(); SFENCE();
  }

#undef STAGE4
#undef READ_A
#undef READ_B
#undef MFMA_Q

  // ---- epilogue: v = sc*(|z|^2+|e|^2) + (-2 sc)*dot ; per-column online max/sumexp
  const float lsv = log_sigma[0];
  const float sc  = -0.5f * __expf(-2.0f * lsv);
  const float n2s = -2.0f * sc;

  float z2v[8][4];
  {
    const float* z2p = (const float*)(ws + Z2_OFF) + nblk * 256 + wr * 128 + ((lane >> 4) << 2);
    #pragma unroll
    for (int i = 0; i < 8; ++i)
      #pragma unroll
      for (int r = 0; r < 4; ++r) z2v[i][r] = z2p[i * 16 + r];
  }
  float e2v[4];
  {
    const float* e2p = (const float*)(ws + E2_OFF) + mblk * 256 + wc * 64 + rl;
    #pragma unroll
    for (int j = 0; j < 4; ++j) e2v[j] = e2p[j * 16];
  }

  float* lmax = (float*)lds;              // [2][256] reuse (all LDS reads drained)
  float* lsum = (float*)(lds + 2048);

  #pragma unroll
  for (int j = 0; j < 4; ++j) {
    float mx = -1e30f;
    #pragma unroll
    for (int i = 0; i < 8; ++i)
      #pragma unroll
      for (int r = 0; r < 4; ++r) {
        float v = fmaf(n2s, acc[i][j][r], sc * (z2v[i][r] + e2v[j]));
        acc[i][j][r] = v;                 // in-place: no vals[] register cost
        mx = fmaxf(mx, v);
      }
    float sm = 0.0f;
    #pragma unroll
    for (int i = 0; i < 8; ++i)
      #pragma unroll
      for (int r = 0; r < 4; ++r) sm += __expf(acc[i][j][r] - mx);

    // fold the 4 lanes sharing a column (lane ^16, ^32)
    #pragma unroll
    for (int mk = 16; mk <= 32; mk <<= 1) {
      float om = __shfl_xor(mx, mk, 64);
      float os = __shfl_xor(sm, mk, 64);
      float nm = fmaxf(mx, om);
      sm = sm * __expf(mx - nm) + os * __expf(om - nm);
      mx = nm;
    }
    if (lane < 16) {
      const int col = wc * 64 + j * 16 + lane;
      lmax[wr * 256 + col] = mx;
      lsum[wr * 256 + col] = sm;
    }
  }
  __syncthreads();

  if (tid < 256) {
    const float m0 = lmax[tid],       s0 = lsum[tid];
    const float m1 = lmax[256 + tid], s1 = lsum[256 + tid];
    const float Mx = fmaxf(m0, m1);
    const float S  = s0 * __expf(m0 - Mx) + s1 * __expf(m1 - Mx);
    float* pmax = (float*)(ws + PMAX_OFF);
    float* psum = (float*)(ws + PSUM_OFF);
    const size_t idx = (size_t)nblk * M_PTS + mblk * 256 + tid;
    pmax[idx] = Mx;
    psum[idx] = S;
  }
}

// ---------------------------------------------------------------------------
// Kernel 3: combine 32 n-block partials per column -> lse[m]; block-reduce
// the lse sum; atomicAdd into ws; last-done block writes the final loss.
// ---------------------------------------------------------------------------
__global__ __launch_bounds__(256) void combine_finalize_kernel(char* __restrict__ ws,
                                                               const float* __restrict__ log_sigma,
                                                               float* __restrict__ out) {
  const int m = blockIdx.x * 256 + threadIdx.x;   // 8192 total
  const float* pmax = (const float*)(ws + PMAX_OFF);
  const float* psum = (const float*)(ws + PSUM_OFF);
  float Mx = pmax[m];
  float S  = psum[m];
  #pragma unroll
  for (int nb = 1; nb < NB; ++nb) {
    const float pm = pmax[(size_t)nb * M_PTS + m];
    const float ps = psum[(size_t)nb * M_PTS + m];
    const float nm = fmaxf(Mx, pm);
    S = S * __expf(Mx - nm) + ps * __expf(pm - nm);
    Mx = nm;
  }
  double lse = (double)Mx + (double)logf(S);

  #pragma unroll
  for (int mk = 32; mk >= 1; mk >>= 1) lse += __shfl_xor(lse, mk, 64);
  __shared__ double red[4];
  if ((threadIdx.x & 63) == 0) red[threadIdx.x >> 6] = lse;
  __syncthreads();
  if (threadIdx.x == 0) {
    const double part = red[0] + red[1] + red[2] + red[3];
    double* sum = (double*)(ws + SUM_OFF);
    int* cnt = (int*)(ws + CNT_OFF);
    atomicAdd(sum, part);
    __threadfence();
    const int old = atomicAdd(cnt, 1);
    if (old == (M_PTS / 256) - 1) {
      const double total = atomicAdd(sum, 0.0);   // coherent read
      const double ls = (double)log_sigma[0];
      const double loss = -total / (double)M_PTS
                          + 0.5 * (double)DIM * (2.0 * ls - 1.0)
                          + log((double)N_PTS);
      out[0] = (float)loss;
    }
  }
}

extern "C" void kernel_launch(void* const* d_in, const int* in_sizes, int n_in,
                              void* d_out, int out_size, void* d_ws, size_t ws_size,
                              hipStream_t stream) {
  const float* z  = (const float*)d_in[0];
  const float* e  = (const float*)d_in[1];
  const float* ls = (const float*)d_in[2];
  float* out = (float*)d_out;
  char* ws = (char*)d_ws;

  conv_kernel<<<(N_PTS + M_PTS) / 4, 256, 0, stream>>>(z, e, ws);
  gemm_lse_kernel<<<(M_PTS / 256) * (N_PTS / 256), 512, 0, stream>>>(ws, ls);
  combine_finalize_kernel<<<M_PTS / 256, 256, 0, stream>>>(ws, ls, out);
}